// Round 3
// baseline (265.932 us; speedup 1.0000x reference)
//
#include <hip/hip_runtime.h>
#include <hip/hip_bf16.h>
#include <cstdint>

// GCN layer: y = relu(dnorm_n * (adj @ (dnorm_m * x @ W)) + b)
// B=128, N=512, F_IN=F_OUT=128, fp32 in/out. bf16 MFMA internally.
//
// v4: round-0 proven 128-tile GEMM geometry everywhere; ONE structural change:
//   FAST (ws >= 84.2 MB):
//     k_degcvt : one pass adj fp32 -> dnorm + adjb bf16 (k_deg + 2 stores)
//     k_agg_bf : r0 k_agg with stage-A = pure bf16 copy (stage-B pattern clone)
//   FALLBACK: exact round-0 kernels (k_deg + convert-staging k_agg).

#define BATCH 128
#define NN    512
#define FIN   128
#define FOUT  128

typedef unsigned short u16;
typedef __attribute__((ext_vector_type(8))) __bf16 bfrag;   // 8 bf16 = 4 VGPRs
typedef __attribute__((ext_vector_type(4))) float  f32x4;

__device__ __forceinline__ u16 f2bf(float f) {
    uint32_t u = __builtin_bit_cast(uint32_t, f);
    u += 0x7fffu + ((u >> 16) & 1u);          // round-nearest-even
    return (u16)(u >> 16);
}
__device__ __forceinline__ ushort4 f2bf4(float4 v) {
    ushort4 r;
    r.x = f2bf(v.x); r.y = f2bf(v.y); r.z = f2bf(v.z); r.w = f2bf(v.w);
    return r;
}

// ---------------- k_prep: Wt[g][k] = bf16(W[k][g]) --------------------------
__global__ __launch_bounds__(256) void k_prep(const float* __restrict__ W,
                                              u16* __restrict__ Wt) {
    int idx = blockIdx.x * 256 + threadIdx.x;   // grid 64 -> 16384 elements
    int g = idx >> 7, k = idx & 127;
    Wt[idx] = f2bf(W[k * FOUT + g]);
}

// ---------------- k_deg: dnorm[row] = rsqrt(rowsum(adj)) (fallback) ---------
__global__ __launch_bounds__(256) void k_deg(const float* __restrict__ adj,
                                             float* __restrict__ dnorm) {
    int wave = threadIdx.x >> 6;
    int lane = threadIdx.x & 63;
    int row  = (blockIdx.x << 2) + wave;          // [0, B*N)
    const float4* p = (const float4*)(adj + (size_t)row * NN);
    float4 v0 = p[lane];
    float4 v1 = p[lane + 64];
    float s = v0.x + v0.y + v0.z + v0.w + v1.x + v1.y + v1.z + v1.w;
    #pragma unroll
    for (int off = 32; off > 0; off >>= 1) s += __shfl_down(s, off, 64);
    if (lane == 0) dnorm[row] = (s > 0.f) ? rsqrtf(s) : 0.f;
}

// ---------------- k_degcvt: dnorm + adjb = bf16(adj) in one pass (fast) -----
__global__ __launch_bounds__(256) void k_degcvt(const float* __restrict__ adj,
                                                u16* __restrict__ adjb,
                                                float* __restrict__ dnorm) {
    int wave = threadIdx.x >> 6;
    int lane = threadIdx.x & 63;
    int row  = (blockIdx.x << 2) + wave;          // [0, B*N)
    const float4* p = (const float4*)(adj + (size_t)row * NN);
    float4 v0 = p[lane];
    float4 v1 = p[lane + 64];
    u16* ob = adjb + (size_t)row * NN;
    *(ushort4*)(ob + (lane << 2))       = f2bf4(v0);   // elems 0..255
    *(ushort4*)(ob + (lane << 2) + 256) = f2bf4(v1);   // elems 256..511
    float s = v0.x + v0.y + v0.z + v0.w + v1.x + v1.y + v1.z + v1.w;
    #pragma unroll
    for (int off = 32; off > 0; off >>= 1) s += __shfl_down(s, off, 64);
    if (lane == 0) dnorm[row] = (s > 0.f) ? rsqrtf(s) : 0.f;
}

// ---------------- k_xw: h1t[b][g][m] = bf16(dnorm[bm] * (x @ W)[bm][g]) -----
// round-0 proven: 128-row tile x 128 cols; 4 waves, each 4x4 of 16x16x32 MFMA
__global__ __launch_bounds__(256) void k_xw(const float* __restrict__ x,
                                            const u16* __restrict__ Wt,
                                            const float* __restrict__ dnorm,
                                            u16* __restrict__ h1t) {
    __shared__ u16 As[128][40];   // As[m][k] bf16, row pad to 40 (80 B)
    __shared__ u16 Bs[128][40];   // Bs[g][k] bf16 (Wt is already [g][k])
    __shared__ float sDn[128];

    int tid  = threadIdx.x;
    int row0 = blockIdx.x * 128;                 // global node-row base
    int wave = tid >> 6, lane = tid & 63;
    int wr = wave >> 1, wc = wave & 1;
    int q = lane >> 4, l16 = lane & 15;

    if (tid < 128) sDn[tid] = dnorm[row0 + tid];

    f32x4 acc[4][4];
    #pragma unroll
    for (int i = 0; i < 4; i++)
        #pragma unroll
        for (int j = 0; j < 4; j++) acc[i][j] = (f32x4)(0.f);

    for (int kt = 0; kt < FIN; kt += 32) {
        // stage A: x fp32 -> bf16 (128 m-rows x 32 k)
        #pragma unroll
        for (int j = 0; j < 4; j++) {
            int linear = tid + j * 256;          // 0..1023 float4 slots
            int m = linear >> 3, k4 = (linear & 7) << 2;
            float4 v = *(const float4*)(x + (size_t)(row0 + m) * FIN + kt + k4);
            *(ushort4*)&As[m][k4] = f2bf4(v);
        }
        // stage B: Wt bf16, 128 g-rows x 32 k = 512 uint4 slots (4 per row)
        #pragma unroll
        for (int j = 0; j < 2; j++) {
            int linear = tid + j * 256;          // 0..511
            int g = linear >> 2, k8 = (linear & 3) << 3;
            *(uint4*)&Bs[g][k8] = *(const uint4*)(Wt + (size_t)g * FIN + kt + k8);
        }
        __syncthreads();
        bfrag aF[4], bF[4];
        #pragma unroll
        for (int i = 0; i < 4; i++) aF[i] = *(const bfrag*)&As[wr * 64 + i * 16 + l16][q * 8];
        #pragma unroll
        for (int j = 0; j < 4; j++) bF[j] = *(const bfrag*)&Bs[wc * 64 + j * 16 + l16][q * 8];
        #pragma unroll
        for (int i = 0; i < 4; i++)
            #pragma unroll
            for (int j = 0; j < 4; j++)
                acc[i][j] = __builtin_amdgcn_mfma_f32_16x16x32_bf16(aF[i], bF[j], acc[i][j], 0, 0, 0);
        __syncthreads();
    }

    // epilogue: scale rows by dnorm, store transposed bf16
    int bb = row0 >> 9;                  // batch
    int mb = row0 & 511;                 // node base within batch
    #pragma unroll
    for (int i = 0; i < 4; i++) {
        int mloc = wr * 64 + i * 16 + q * 4;
        float d0 = sDn[mloc], d1 = sDn[mloc + 1], d2 = sDn[mloc + 2], d3 = sDn[mloc + 3];
        #pragma unroll
        for (int j = 0; j < 4; j++) {
            int g = wc * 64 + j * 16 + l16;
            f32x4 c = acc[i][j];
            ushort4 v;
            v.x = f2bf(c[0] * d0); v.y = f2bf(c[1] * d1);
            v.z = f2bf(c[2] * d2); v.w = f2bf(c[3] * d3);
            *(ushort4*)(h1t + ((size_t)bb * FOUT + g) * NN + mb + mloc) = v;
        }
    }
}

// ---------------- k_agg_bf: r0 k_agg, stage-A = pure bf16 copy (fast) -------
__global__ __launch_bounds__(256) void k_agg_bf(const u16* __restrict__ adjb,
                                                const u16* __restrict__ h1t,
                                                const float* __restrict__ dnorm,
                                                const float* __restrict__ bias,
                                                float* __restrict__ out) {
    __shared__ u16 As[128][40];   // As[n][k] = adjb[b][n0+n][kt+k]
    __shared__ u16 Bs[128][40];   // Bs[g][k] = h1t[b][g][kt+k]
    __shared__ float sDn[128];
    __shared__ float sBias[128];

    int tid = threadIdx.x;
    int b   = blockIdx.y;
    int n0  = blockIdx.x * 128;
    int wave = tid >> 6, lane = tid & 63;
    int wr = wave >> 1, wc = wave & 1;
    int q = lane >> 4, l16 = lane & 15;

    const u16* Ab = adjb + ((size_t)b * NN + n0) * NN;
    const u16* Bm = h1t + (size_t)b * FOUT * NN;
    if (tid < 128) { sDn[tid] = dnorm[(size_t)b * NN + n0 + tid]; sBias[tid] = bias[tid]; }

    f32x4 acc[4][4];
    #pragma unroll
    for (int i = 0; i < 4; i++)
        #pragma unroll
        for (int j = 0; j < 4; j++) acc[i][j] = (f32x4)(0.f);

    for (int kt = 0; kt < NN; kt += 32) {
        // stage A: adjb bf16 copy, 128 n x 32 k = 512 uint4 slots (4 per row)
        #pragma unroll
        for (int j = 0; j < 2; j++) {
            int linear = tid + j * 256;          // 0..511 slots of 16 B
            int m = linear >> 2, k8 = (linear & 3) << 3;
            *(uint4*)&As[m][k8] = *(const uint4*)(Ab + (size_t)m * NN + kt + k8);
        }
        // stage B: h1t bf16 copy, 128 g x 32 k (4 uint4 slots per g)
        #pragma unroll
        for (int j = 0; j < 2; j++) {
            int linear = tid + j * 256;          // 0..511 slots of 16 B
            int g = linear >> 2, k8 = (linear & 3) << 3;
            *(uint4*)&Bs[g][k8] = *(const uint4*)(Bm + (size_t)g * NN + kt + k8);
        }
        __syncthreads();
        bfrag aF[4], bF[4];
        #pragma unroll
        for (int i = 0; i < 4; i++) aF[i] = *(const bfrag*)&As[wr * 64 + i * 16 + l16][q * 8];
        #pragma unroll
        for (int j = 0; j < 4; j++) bF[j] = *(const bfrag*)&Bs[wc * 64 + j * 16 + l16][q * 8];
        #pragma unroll
        for (int i = 0; i < 4; i++)
            #pragma unroll
            for (int j = 0; j < 4; j++)
                acc[i][j] = __builtin_amdgcn_mfma_f32_16x16x32_bf16(aF[i], bF[j], acc[i][j], 0, 0, 0);
        __syncthreads();
    }

    // epilogue: dnorm_n scale + bias + relu, fp32 store
    #pragma unroll
    for (int i = 0; i < 4; i++) {
        int rloc = wr * 64 + i * 16 + q * 4;
        float d0 = sDn[rloc], d1 = sDn[rloc + 1], d2 = sDn[rloc + 2], d3 = sDn[rloc + 3];
        #pragma unroll
        for (int j = 0; j < 4; j++) {
            int col = wc * 64 + j * 16 + l16;
            float bsv = sBias[col];
            f32x4 c = acc[i][j];
            float* o = out + ((size_t)b * NN + n0 + rloc) * FOUT + col;
            o[0 * FOUT] = fmaxf(fmaf(c[0], d0, bsv), 0.f);
            o[1 * FOUT] = fmaxf(fmaf(c[1], d1, bsv), 0.f);
            o[2 * FOUT] = fmaxf(fmaf(c[2], d2, bsv), 0.f);
            o[3 * FOUT] = fmaxf(fmaf(c[3], d3, bsv), 0.f);
        }
    }
}

// ---------------- k_agg_f32: round-0 k_agg verbatim (fallback) --------------
__global__ __launch_bounds__(256) void k_agg_f32(const float* __restrict__ adj,
                                                 const u16* __restrict__ h1t,
                                                 const float* __restrict__ dnorm,
                                                 const float* __restrict__ bias,
                                                 float* __restrict__ out) {
    __shared__ u16 As[128][40];
    __shared__ u16 Bs[128][40];
    __shared__ float sDn[128];
    __shared__ float sBias[128];

    int tid = threadIdx.x;
    int b   = blockIdx.y;
    int n0  = blockIdx.x * 128;
    int wave = tid >> 6, lane = tid & 63;
    int wr = wave >> 1, wc = wave & 1;
    int q = lane >> 4, l16 = lane & 15;

    const float* A   = adj + (size_t)b * NN * NN;
    const u16*   Bm  = h1t + (size_t)b * FOUT * NN;
    if (tid < 128) { sDn[tid] = dnorm[(size_t)b * NN + n0 + tid]; sBias[tid] = bias[tid]; }

    f32x4 acc[4][4];
    #pragma unroll
    for (int i = 0; i < 4; i++)
        #pragma unroll
        for (int j = 0; j < 4; j++) acc[i][j] = (f32x4)(0.f);

    for (int kt = 0; kt < NN; kt += 32) {
        #pragma unroll
        for (int j = 0; j < 4; j++) {
            int linear = tid + j * 256;
            int m = linear >> 3, k4 = (linear & 7) << 2;
            float4 v = *(const float4*)(A + (size_t)(n0 + m) * NN + kt + k4);
            *(ushort4*)&As[m][k4] = f2bf4(v);
        }
        #pragma unroll
        for (int j = 0; j < 2; j++) {
            int linear = tid + j * 256;
            int g = linear >> 2, k8 = (linear & 3) << 3;
            *(uint4*)&Bs[g][k8] = *(const uint4*)(Bm + (size_t)g * NN + kt + k8);
        }
        __syncthreads();
        bfrag aF[4], bF[4];
        #pragma unroll
        for (int i = 0; i < 4; i++) aF[i] = *(const bfrag*)&As[wr * 64 + i * 16 + l16][q * 8];
        #pragma unroll
        for (int j = 0; j < 4; j++) bF[j] = *(const bfrag*)&Bs[wc * 64 + j * 16 + l16][q * 8];
        #pragma unroll
        for (int i = 0; i < 4; i++)
            #pragma unroll
            for (int j = 0; j < 4; j++)
                acc[i][j] = __builtin_amdgcn_mfma_f32_16x16x32_bf16(aF[i], bF[j], acc[i][j], 0, 0, 0);
        __syncthreads();
    }

    #pragma unroll
    for (int i = 0; i < 4; i++) {
        int rloc = wr * 64 + i * 16 + q * 4;
        float d0 = sDn[rloc], d1 = sDn[rloc + 1], d2 = sDn[rloc + 2], d3 = sDn[rloc + 3];
        #pragma unroll
        for (int j = 0; j < 4; j++) {
            int col = wc * 64 + j * 16 + l16;
            float bsv = sBias[col];
            f32x4 c = acc[i][j];
            float* o = out + ((size_t)b * NN + n0 + rloc) * FOUT + col;
            o[0 * FOUT] = fmaxf(fmaf(c[0], d0, bsv), 0.f);
            o[1 * FOUT] = fmaxf(fmaf(c[1], d1, bsv), 0.f);
            o[2 * FOUT] = fmaxf(fmaf(c[2], d2, bsv), 0.f);
            o[3 * FOUT] = fmaxf(fmaf(c[3], d3, bsv), 0.f);
        }
    }
}

extern "C" void kernel_launch(void* const* d_in, const int* in_sizes, int n_in,
                              void* d_out, int out_size, void* d_ws, size_t ws_size,
                              hipStream_t stream) {
    const float* adj  = (const float*)d_in[0];
    const float* x    = (const float*)d_in[1];
    const float* W    = (const float*)d_in[2];
    const float* bias = (const float*)d_in[3];
    float* out = (float*)d_out;

    char* ws = (char*)d_ws;
    float* dnorm = (float*)ws;                                   // 65536 f32 = 256 KB
    u16*   Wt    = (u16*)(ws + 262144);                          // 16384 bf16 = 32 KB
    u16*   h1t   = (u16*)(ws + 262144 + 32768);                  // 8.4M bf16 = 16.8 MB
    u16*   adjb  = (u16*)(ws + 262144 + 32768 + 16777216);       // 33.5M bf16 = 67.1 MB

    const size_t need_fast = 262144ull + 32768ull + 16777216ull + 67108864ull;  // 84.2 MB

    hipLaunchKernelGGL(k_prep, dim3(64), dim3(256), 0, stream, W, Wt);

    if (ws_size >= need_fast) {
        hipLaunchKernelGGL(k_degcvt, dim3(BATCH * NN / 4), dim3(256), 0, stream, adj, adjb, dnorm);
        hipLaunchKernelGGL(k_xw,     dim3(BATCH * NN / 128), dim3(256), 0, stream, x, Wt, dnorm, h1t);
        hipLaunchKernelGGL(k_agg_bf, dim3(4, BATCH), dim3(256), 0, stream, adjb, h1t, dnorm, bias, out);
    } else {
        hipLaunchKernelGGL(k_deg,     dim3(BATCH * NN / 4), dim3(256), 0, stream, adj, dnorm);
        hipLaunchKernelGGL(k_xw,      dim3(BATCH * NN / 128), dim3(256), 0, stream, x, Wt, dnorm, h1t);
        hipLaunchKernelGGL(k_agg_f32, dim3(4, BATCH), dim3(256), 0, stream, adj, h1t, dnorm, bias, out);
    }
}

// Round 4
// 253.414 us; speedup vs baseline: 1.0494x; 1.0494x over previous
//
#include <hip/hip_runtime.h>
#include <hip/hip_bf16.h>
#include <cstdint>

// GCN layer: y = relu(dnorm_n * (adj @ (dnorm_m * x @ W)) + b)
// B=128, N=512, F_IN=F_OUT=128, fp32 in/out. bf16 MFMA internally.
//
// v5: fused structure.
//   k_prep  : Wt[g][k] = bf16(W[k][g])                      (tiny, proven)
//   k_deg   : dnorm = rsqrt(rowsum(adj))                    (proven)
//   k_fused : per (batch, half): phase 1 computes FULL h1[b] = bf16(Dm*(X@W))
//             into LDS (131 KB); phase 2 aggregates out = relu(Dn*(adj@h1)+b)
//             with B-operand read straight from LDS (no staging, no h1t HBM).
//   Grid 256 blocks = 1/CU, 512 threads (8 waves). All MFMA patterns cloned
//   from the r0-proven kernels -> bit-identical numerics.

#define BATCH 128
#define NN    512
#define FIN   128
#define FOUT  128

typedef unsigned short u16;
typedef __attribute__((ext_vector_type(8))) __bf16 bfrag;   // 8 bf16 = 4 VGPRs
typedef __attribute__((ext_vector_type(4))) float  f32x4;

__device__ __forceinline__ u16 f2bf(float f) {
    uint32_t u = __builtin_bit_cast(uint32_t, f);
    u += 0x7fffu + ((u >> 16) & 1u);          // round-nearest-even
    return (u16)(u >> 16);
}
__device__ __forceinline__ ushort4 f2bf4(float4 v) {
    ushort4 r;
    r.x = f2bf(v.x); r.y = f2bf(v.y); r.z = f2bf(v.z); r.w = f2bf(v.w);
    return r;
}

// ---------------- k_prep: Wt[g][k] = bf16(W[k][g]) --------------------------
__global__ __launch_bounds__(256) void k_prep(const float* __restrict__ W,
                                              u16* __restrict__ Wt) {
    int idx = blockIdx.x * 256 + threadIdx.x;   // grid 64 -> 16384 elements
    int g = idx >> 7, k = idx & 127;
    Wt[idx] = f2bf(W[k * FOUT + g]);
}

// ---------------- k_deg: dnorm[row] = rsqrt(rowsum(adj)) --------------------
__global__ __launch_bounds__(256) void k_deg(const float* __restrict__ adj,
                                             float* __restrict__ dnorm) {
    int wave = threadIdx.x >> 6;
    int lane = threadIdx.x & 63;
    int row  = (blockIdx.x << 2) + wave;          // [0, B*N)
    const float4* p = (const float4*)(adj + (size_t)row * NN);
    float4 v0 = p[lane];
    float4 v1 = p[lane + 64];
    float s = v0.x + v0.y + v0.z + v0.w + v1.x + v1.y + v1.z + v1.w;
    #pragma unroll
    for (int off = 32; off > 0; off >>= 1) s += __shfl_down(s, off, 64);
    if (lane == 0) dnorm[row] = (s > 0.f) ? rsqrtf(s) : 0.f;
}

// ---------------- k_fused: h1 in LDS, then aggregate ------------------------
// blockIdx = (half, b). 512 threads = 8 waves.
// Phase 1: h1[b] (512 m x 128 g) = bf16(dnorm_m * (X[b] @ W)) -> hs[g][m] LDS.
//   4 chunks of 128 m-rows; per chunk 8 waves as 2x4 (64-row x 32-col groups),
//   each wave 4x2 tiles of 16x16x32 MFMA, K=128 in 4 steps (clone of k_xw).
// Phase 2: out[b][n0..n0+256][:] = relu(Dn * (adj @ h1) + b), K=512 in 16
//   steps; A staged fp32->bf16 (clone of r0 k_agg), B read from hs directly.
__global__ __launch_bounds__(512) void k_fused(const float* __restrict__ x,
                                               const u16* __restrict__ Wt,
                                               const float* __restrict__ adj,
                                               const float* __restrict__ dnorm,
                                               const float* __restrict__ bias,
                                               float* __restrict__ out) {
    __shared__ u16 hs[128][520];          // h1t[g][m], pad 512->520 (133.1 KB)
    __shared__ float sDn[512];            // dnorm for the whole batch
    __shared__ float sBias[128];
    __shared__ union {
        struct { u16 As[128][40]; u16 Bs[128][40]; } p1;   // phase-1 staging
        u16 As2[256][40];                                  // phase-2 staging
    } u;                                                   // 20.5 KB

    int tid  = threadIdx.x;               // 0..511
    int b    = blockIdx.y;
    int n0   = blockIdx.x * 256;          // out-row base (0 or 256)
    int wave = tid >> 6, lane = tid & 63;
    int q = lane >> 4, l16 = lane & 15;

    sDn[tid] = dnorm[(size_t)b * NN + tid];
    if (tid < 128) sBias[tid] = bias[tid];

    // ---------------- phase 1: h1[b] -> hs ----------------
    {
        int wr1 = wave >> 2;              // 0..1  (64-row group)
        int wc1 = wave & 3;               // 0..3  (32-col group)
        for (int c = 0; c < 4; c++) {
            int m0 = c * 128;
            f32x4 acc2[4][2];
            #pragma unroll
            for (int i = 0; i < 4; i++)
                #pragma unroll
                for (int j = 0; j < 2; j++) acc2[i][j] = (f32x4)(0.f);

            for (int kt = 0; kt < FIN; kt += 32) {
                // stage A: x[b][m0..m0+128][kt..kt+32] fp32 -> bf16
                #pragma unroll
                for (int jj = 0; jj < 2; jj++) {
                    int linear = tid + jj * 512;     // 0..1023
                    int m = linear >> 3, k4 = (linear & 7) << 2;
                    float4 v = *(const float4*)(x + ((size_t)b * NN + m0 + m) * FIN + kt + k4);
                    *(ushort4*)&u.p1.As[m][k4] = f2bf4(v);
                }
                // stage B: Wt[g][kt..kt+32] bf16 copy (1 uint4/thread)
                {
                    int g = tid >> 2, k8 = (tid & 3) << 3;
                    *(uint4*)&u.p1.Bs[g][k8] = *(const uint4*)(Wt + (size_t)g * FIN + kt + k8);
                }
                __syncthreads();
                bfrag aF[4], bF[2];
                #pragma unroll
                for (int i = 0; i < 4; i++) aF[i] = *(const bfrag*)&u.p1.As[wr1 * 64 + i * 16 + l16][q * 8];
                #pragma unroll
                for (int j = 0; j < 2; j++) bF[j] = *(const bfrag*)&u.p1.Bs[wc1 * 32 + j * 16 + l16][q * 8];
                #pragma unroll
                for (int i = 0; i < 4; i++)
                    #pragma unroll
                    for (int j = 0; j < 2; j++)
                        acc2[i][j] = __builtin_amdgcn_mfma_f32_16x16x32_bf16(aF[i], bF[j], acc2[i][j], 0, 0, 0);
                __syncthreads();
            }
            // epilogue: Dm scale + round, store hs[g][m] (4 consecutive m)
            #pragma unroll
            for (int i = 0; i < 4; i++) {
                int mb = m0 + wr1 * 64 + i * 16 + q * 4;
                float d0 = sDn[mb], d1 = sDn[mb + 1], d2 = sDn[mb + 2], d3 = sDn[mb + 3];
                #pragma unroll
                for (int j = 0; j < 2; j++) {
                    int g = wc1 * 32 + j * 16 + l16;
                    f32x4 cc = acc2[i][j];
                    ushort4 v;
                    v.x = f2bf(cc[0] * d0); v.y = f2bf(cc[1] * d1);
                    v.z = f2bf(cc[2] * d2); v.w = f2bf(cc[3] * d3);
                    *(ushort4*)&hs[g][mb] = v;
                }
            }
        }
    }
    __syncthreads();   // hs complete; p1 staging dead -> As2 may overwrite

    // ---------------- phase 2: out = relu(Dn * (adj @ hs) + b) ----------------
    {
        int wr = wave >> 1;               // 0..3  (64-row group of 256)
        int wc = wave & 1;                // 0..1  (64-col group)
        f32x4 acc[4][4];
        #pragma unroll
        for (int i = 0; i < 4; i++)
            #pragma unroll
            for (int j = 0; j < 4; j++) acc[i][j] = (f32x4)(0.f);

        for (int kt = 0; kt < NN; kt += 32) {
            // stage A: adj[b][n0..n0+256][kt..kt+32] fp32 -> bf16 (4/thread)
            #pragma unroll
            for (int jj = 0; jj < 4; jj++) {
                int linear = tid + jj * 512;         // 0..2047
                int m = linear >> 3, k4 = (linear & 7) << 2;
                float4 v = *(const float4*)(adj + ((size_t)b * NN + n0 + m) * NN + kt + k4);
                *(ushort4*)&u.As2[m][k4] = f2bf4(v);
            }
            __syncthreads();
            bfrag aF[4], bF[4];
            #pragma unroll
            for (int i = 0; i < 4; i++) aF[i] = *(const bfrag*)&u.As2[wr * 64 + i * 16 + l16][q * 8];
            #pragma unroll
            for (int j = 0; j < 4; j++) bF[j] = *(const bfrag*)&hs[wc * 64 + j * 16 + l16][kt + q * 8];
            #pragma unroll
            for (int i = 0; i < 4; i++)
                #pragma unroll
                for (int j = 0; j < 4; j++)
                    acc[i][j] = __builtin_amdgcn_mfma_f32_16x16x32_bf16(aF[i], bF[j], acc[i][j], 0, 0, 0);
            __syncthreads();
        }

        // epilogue: Dn scale + bias + relu, fp32 store
        #pragma unroll
        for (int i = 0; i < 4; i++) {
            int rloc = wr * 64 + i * 16 + q * 4;
            float d0 = sDn[n0 + rloc],     d1 = sDn[n0 + rloc + 1];
            float d2 = sDn[n0 + rloc + 2], d3 = sDn[n0 + rloc + 3];
            #pragma unroll
            for (int j = 0; j < 4; j++) {
                int col = wc * 64 + j * 16 + l16;
                float bsv = sBias[col];
                f32x4 c = acc[i][j];
                float* o = out + ((size_t)b * NN + n0 + rloc) * FOUT + col;
                o[0 * FOUT] = fmaxf(fmaf(c[0], d0, bsv), 0.f);
                o[1 * FOUT] = fmaxf(fmaf(c[1], d1, bsv), 0.f);
                o[2 * FOUT] = fmaxf(fmaf(c[2], d2, bsv), 0.f);
                o[3 * FOUT] = fmaxf(fmaf(c[3], d3, bsv), 0.f);
            }
        }
    }
}

extern "C" void kernel_launch(void* const* d_in, const int* in_sizes, int n_in,
                              void* d_out, int out_size, void* d_ws, size_t ws_size,
                              hipStream_t stream) {
    const float* adj  = (const float*)d_in[0];
    const float* x    = (const float*)d_in[1];
    const float* W    = (const float*)d_in[2];
    const float* bias = (const float*)d_in[3];
    float* out = (float*)d_out;

    char* ws = (char*)d_ws;
    float* dnorm = (float*)ws;                                   // 65536 f32 = 256 KB
    u16*   Wt    = (u16*)(ws + 262144);                          // 16384 bf16 = 32 KB

    hipLaunchKernelGGL(k_prep,  dim3(64), dim3(256), 0, stream, W, Wt);
    hipLaunchKernelGGL(k_deg,   dim3(BATCH * NN / 4), dim3(256), 0, stream, adj, dnorm);
    hipLaunchKernelGGL(k_fused, dim3(2, BATCH), dim3(512), 0, stream,
                       x, Wt, adj, dnorm, bias, out);
}

// Round 5
// 246.911 us; speedup vs baseline: 1.0770x; 1.0263x over previous
//
#include <hip/hip_runtime.h>
#include <hip/hip_bf16.h>
#include <cstdint>

// GCN layer: y = relu(dnorm_n * (adj @ (dnorm_m * x @ W)) + b)
// B=128, N=512, F_IN=F_OUT=128, fp32 in/out. bf16 MFMA internally.
//
// v6 = v5 fused structure + latency attack:
//   phase 1: Wt preloaded to registers (no B-staging), x staged in K=64 halves
//            -> 16 barriers/block instead of 32; identical kt accumulation order.
//   phase 2: T14 register double-buffer -- next K-step's adj loads issued
//            between the barriers so HBM latency hides under ds_read+MFMA.
// All MFMA fragment patterns / accumulation order cloned from v5 (bit-identical).

#define BATCH 128
#define NN    512
#define FIN   128
#define FOUT  128

typedef unsigned short u16;
typedef __attribute__((ext_vector_type(8))) __bf16 bfrag;   // 8 bf16 = 4 VGPRs
typedef __attribute__((ext_vector_type(4))) float  f32x4;

__device__ __forceinline__ u16 f2bf(float f) {
    uint32_t u = __builtin_bit_cast(uint32_t, f);
    u += 0x7fffu + ((u >> 16) & 1u);          // round-nearest-even
    return (u16)(u >> 16);
}
__device__ __forceinline__ ushort4 f2bf4(float4 v) {
    ushort4 r;
    r.x = f2bf(v.x); r.y = f2bf(v.y); r.z = f2bf(v.z); r.w = f2bf(v.w);
    return r;
}

// ---------------- k_prep: Wt[g][k] = bf16(W[k][g]) --------------------------
__global__ __launch_bounds__(256) void k_prep(const float* __restrict__ W,
                                              u16* __restrict__ Wt) {
    int idx = blockIdx.x * 256 + threadIdx.x;   // grid 64 -> 16384 elements
    int g = idx >> 7, k = idx & 127;
    Wt[idx] = f2bf(W[k * FOUT + g]);
}

// ---------------- k_deg: dnorm[row] = rsqrt(rowsum(adj)) --------------------
__global__ __launch_bounds__(256) void k_deg(const float* __restrict__ adj,
                                             float* __restrict__ dnorm) {
    int wave = threadIdx.x >> 6;
    int lane = threadIdx.x & 63;
    int row  = (blockIdx.x << 2) + wave;          // [0, B*N)
    const float4* p = (const float4*)(adj + (size_t)row * NN);
    float4 v0 = p[lane];
    float4 v1 = p[lane + 64];
    float s = v0.x + v0.y + v0.z + v0.w + v1.x + v1.y + v1.z + v1.w;
    #pragma unroll
    for (int off = 32; off > 0; off >>= 1) s += __shfl_down(s, off, 64);
    if (lane == 0) dnorm[row] = (s > 0.f) ? rsqrtf(s) : 0.f;
}

// ---------------- k_fused: h1 in LDS, then aggregate ------------------------
// blockIdx = (half, b). 512 threads = 8 waves.
__global__ __launch_bounds__(512) void k_fused(const float* __restrict__ x,
                                               const u16* __restrict__ Wt,
                                               const float* __restrict__ adj,
                                               const float* __restrict__ dnorm,
                                               const float* __restrict__ bias,
                                               float* __restrict__ out) {
    __shared__ u16 hs[128][520];          // h1t[g][m], pad 512->520 (130 KiB)
    __shared__ float sDn[512];            // dnorm for the whole batch
    __shared__ float sBias[128];
    __shared__ union {
        u16 As1[128][72];                 // phase-1 x staging (K=64 half)
        u16 As2[256][40];                 // phase-2 adj staging (K=32 step)
    } u;                                  // 20 KiB

    int tid  = threadIdx.x;               // 0..511
    int b    = blockIdx.y;
    int n0   = blockIdx.x * 256;          // out-row base (0 or 256)
    int wave = tid >> 6, lane = tid & 63;
    int q = lane >> 4, l16 = lane & 15;

    sDn[tid] = dnorm[(size_t)b * NN + tid];
    if (tid < 128) sBias[tid] = bias[tid];

    // ---------------- phase 1: h1[b] -> hs ----------------
    {
        int wr1 = wave >> 2;              // 0..1  (64-row group)
        int wc1 = wave & 3;               // 0..3  (32-col group)

        // Wt fragments for this wave's 32-col group, all K=128, in registers.
        // wreg[kt4][j] == old Bs read at kt = kt4*32: Wt[g][kt4*32 + q*8 ..]
        bfrag wreg[4][2];
        #pragma unroll
        for (int kt4 = 0; kt4 < 4; kt4++)
            #pragma unroll
            for (int j = 0; j < 2; j++) {
                int g = wc1 * 32 + j * 16 + l16;
                wreg[kt4][j] = *(const bfrag*)(Wt + (size_t)g * FIN + kt4 * 32 + q * 8);
            }

        for (int c = 0; c < 4; c++) {
            int m0 = c * 128;
            f32x4 acc2[4][2];
            #pragma unroll
            for (int i = 0; i < 4; i++)
                #pragma unroll
                for (int j = 0; j < 2; j++) acc2[i][j] = (f32x4)(0.f);

            for (int kh = 0; kh < 2; kh++) {
                // stage A: x[b][m0..m0+128][kh*64..+64] fp32 -> bf16
                // 128 rows x 64 k = 2048 float4 slots, 4/thread
                #pragma unroll
                for (int jj = 0; jj < 4; jj++) {
                    int linear = tid + jj * 512;         // 0..2047
                    int m = linear >> 4, k4 = (linear & 15) << 2;
                    float4 v = *(const float4*)(x + ((size_t)b * NN + m0 + m) * FIN + kh * 64 + k4);
                    *(ushort4*)&u.As1[m][k4] = f2bf4(v);
                }
                __syncthreads();
                #pragma unroll
                for (int kt2 = 0; kt2 < 2; kt2++) {
                    int kt4 = kh * 2 + kt2;              // accumulation order 0,1,2,3
                    bfrag aF[4];
                    #pragma unroll
                    for (int i = 0; i < 4; i++)
                        aF[i] = *(const bfrag*)&u.As1[wr1 * 64 + i * 16 + l16][kt2 * 32 + q * 8];
                    #pragma unroll
                    for (int i = 0; i < 4; i++)
                        #pragma unroll
                        for (int j = 0; j < 2; j++)
                            acc2[i][j] = __builtin_amdgcn_mfma_f32_16x16x32_bf16(aF[i], wreg[kt4][j], acc2[i][j], 0, 0, 0);
                }
                __syncthreads();
            }
            // epilogue: Dm scale + round, store hs[g][m] (4 consecutive m)
            #pragma unroll
            for (int i = 0; i < 4; i++) {
                int mb = m0 + wr1 * 64 + i * 16 + q * 4;
                float d0 = sDn[mb], d1 = sDn[mb + 1], d2 = sDn[mb + 2], d3 = sDn[mb + 3];
                #pragma unroll
                for (int j = 0; j < 2; j++) {
                    int g = wc1 * 32 + j * 16 + l16;
                    f32x4 cc = acc2[i][j];
                    ushort4 v;
                    v.x = f2bf(cc[0] * d0); v.y = f2bf(cc[1] * d1);
                    v.z = f2bf(cc[2] * d2); v.w = f2bf(cc[3] * d3);
                    *(ushort4*)&hs[g][mb] = v;
                }
            }
        }
    }
    __syncthreads();   // hs complete; As1 dead -> As2 may overwrite

    // ---------------- phase 2: out = relu(Dn * (adj @ hs) + b) --------------
    {
        int wr = wave >> 1;               // 0..3  (64-row group of 256)
        int wc = wave & 1;                // 0..1  (64-col group)
        f32x4 acc[4][4];
        #pragma unroll
        for (int i = 0; i < 4; i++)
            #pragma unroll
            for (int j = 0; j < 4; j++) acc[i][j] = (f32x4)(0.f);

        // T14 prologue: issue kt=0 loads
        float4 ld[4];
        #pragma unroll
        for (int jj = 0; jj < 4; jj++) {
            int linear = tid + jj * 512;             // 0..2047
            int m = linear >> 3, k4 = (linear & 7) << 2;
            ld[jj] = *(const float4*)(adj + ((size_t)b * NN + n0 + m) * NN + k4);
        }

        for (int kt = 0; kt < NN; kt += 32) {
            // convert + write current step's staged regs
            #pragma unroll
            for (int jj = 0; jj < 4; jj++) {
                int linear = tid + jj * 512;
                int m = linear >> 3, k4 = (linear & 7) << 2;
                *(ushort4*)&u.As2[m][k4] = f2bf4(ld[jj]);
            }
            __syncthreads();
            // T14: issue NEXT step's loads now -- they fly under ds_read+MFMA
            if (kt + 32 < NN) {
                #pragma unroll
                for (int jj = 0; jj < 4; jj++) {
                    int linear = tid + jj * 512;
                    int m = linear >> 3, k4 = (linear & 7) << 2;
                    ld[jj] = *(const float4*)(adj + ((size_t)b * NN + n0 + m) * NN + kt + 32 + k4);
                }
            }
            bfrag aF[4], bF[4];
            #pragma unroll
            for (int i = 0; i < 4; i++) aF[i] = *(const bfrag*)&u.As2[wr * 64 + i * 16 + l16][q * 8];
            #pragma unroll
            for (int j = 0; j < 4; j++) bF[j] = *(const bfrag*)&hs[wc * 64 + j * 16 + l16][kt + q * 8];
            #pragma unroll
            for (int i = 0; i < 4; i++)
                #pragma unroll
                for (int j = 0; j < 4; j++)
                    acc[i][j] = __builtin_amdgcn_mfma_f32_16x16x32_bf16(aF[i], bF[j], acc[i][j], 0, 0, 0);
            __syncthreads();
        }

        // epilogue: Dn scale + bias + relu, fp32 store
        #pragma unroll
        for (int i = 0; i < 4; i++) {
            int rloc = wr * 64 + i * 16 + q * 4;
            float d0 = sDn[n0 + rloc],     d1 = sDn[n0 + rloc + 1];
            float d2 = sDn[n0 + rloc + 2], d3 = sDn[n0 + rloc + 3];
            #pragma unroll
            for (int j = 0; j < 4; j++) {
                int col = wc * 64 + j * 16 + l16;
                float bsv = sBias[col];
                f32x4 c = acc[i][j];
                float* o = out + ((size_t)b * NN + n0 + rloc) * FOUT + col;
                o[0 * FOUT] = fmaxf(fmaf(c[0], d0, bsv), 0.f);
                o[1 * FOUT] = fmaxf(fmaf(c[1], d1, bsv), 0.f);
                o[2 * FOUT] = fmaxf(fmaf(c[2], d2, bsv), 0.f);
                o[3 * FOUT] = fmaxf(fmaf(c[3], d3, bsv), 0.f);
            }
        }
    }
}

extern "C" void kernel_launch(void* const* d_in, const int* in_sizes, int n_in,
                              void* d_out, int out_size, void* d_ws, size_t ws_size,
                              hipStream_t stream) {
    const float* adj  = (const float*)d_in[0];
    const float* x    = (const float*)d_in[1];
    const float* W    = (const float*)d_in[2];
    const float* bias = (const float*)d_in[3];
    float* out = (float*)d_out;

    char* ws = (char*)d_ws;
    float* dnorm = (float*)ws;                                   // 65536 f32 = 256 KB
    u16*   Wt    = (u16*)(ws + 262144);                          // 16384 bf16 = 32 KB

    hipLaunchKernelGGL(k_prep,  dim3(64), dim3(256), 0, stream, W, Wt);
    hipLaunchKernelGGL(k_deg,   dim3(BATCH * NN / 4), dim3(256), 0, stream, adj, dnorm);
    hipLaunchKernelGGL(k_fused, dim3(2, BATCH), dim3(512), 0, stream,
                       x, Wt, adj, dnorm, bias, out);
}

// Round 6
// 245.814 us; speedup vs baseline: 1.0818x; 1.0045x over previous
//
#include <hip/hip_runtime.h>
#include <hip/hip_bf16.h>
#include <cstdint>

// GCN layer: y = relu(dnorm_n * (adj @ (dnorm_m * x @ W)) + b)
// B=128, N=512, F_IN=F_OUT=128, fp32 in/out. bf16 MFMA internally.
//
// v7 = v6 + deeper HBM pipelining (numerics bit-identical to v5/v6):
//   phase 1: 1-deep register prefetch across all 8 (chunk,half) x-stages.
//   phase 2: 2-deep register prefetch (named lda/ldb buffers, explicit
//            2-step unroll) -> 64 KB/block in flight, covers ~2x the
//            per-CU HBM latency-BW product that v6's 1-deep left exposed.

#define BATCH 128
#define NN    512
#define FIN   128
#define FOUT  128

typedef unsigned short u16;
typedef __attribute__((ext_vector_type(8))) __bf16 bfrag;   // 8 bf16 = 4 VGPRs
typedef __attribute__((ext_vector_type(4))) float  f32x4;

__device__ __forceinline__ u16 f2bf(float f) {
    uint32_t u = __builtin_bit_cast(uint32_t, f);
    u += 0x7fffu + ((u >> 16) & 1u);          // round-nearest-even
    return (u16)(u >> 16);
}
__device__ __forceinline__ ushort4 f2bf4(float4 v) {
    ushort4 r;
    r.x = f2bf(v.x); r.y = f2bf(v.y); r.z = f2bf(v.z); r.w = f2bf(v.w);
    return r;
}

// ---------------- k_prep: Wt[g][k] = bf16(W[k][g]) --------------------------
__global__ __launch_bounds__(256) void k_prep(const float* __restrict__ W,
                                              u16* __restrict__ Wt) {
    int idx = blockIdx.x * 256 + threadIdx.x;   // grid 64 -> 16384 elements
    int g = idx >> 7, k = idx & 127;
    Wt[idx] = f2bf(W[k * FOUT + g]);
}

// ---------------- k_deg: dnorm[row] = rsqrt(rowsum(adj)) --------------------
__global__ __launch_bounds__(256) void k_deg(const float* __restrict__ adj,
                                             float* __restrict__ dnorm) {
    int wave = threadIdx.x >> 6;
    int lane = threadIdx.x & 63;
    int row  = (blockIdx.x << 2) + wave;          // [0, B*N)
    const float4* p = (const float4*)(adj + (size_t)row * NN);
    float4 v0 = p[lane];
    float4 v1 = p[lane + 64];
    float s = v0.x + v0.y + v0.z + v0.w + v1.x + v1.y + v1.z + v1.w;
    #pragma unroll
    for (int off = 32; off > 0; off >>= 1) s += __shfl_down(s, off, 64);
    if (lane == 0) dnorm[row] = (s > 0.f) ? rsqrtf(s) : 0.f;
}

// ---------------- k_fused: h1 in LDS, then aggregate ------------------------
// blockIdx = (half, b). 512 threads = 8 waves.
__global__ __launch_bounds__(512) void k_fused(const float* __restrict__ x,
                                               const u16* __restrict__ Wt,
                                               const float* __restrict__ adj,
                                               const float* __restrict__ dnorm,
                                               const float* __restrict__ bias,
                                               float* __restrict__ out) {
    __shared__ u16 hs[128][520];          // h1t[g][m], pad 512->520 (130 KiB)
    __shared__ float sDn[512];            // dnorm for the whole batch
    __shared__ float sBias[128];
    __shared__ union {
        u16 As1[128][72];                 // phase-1 x staging (K=64 half)
        u16 As2[256][40];                 // phase-2 adj staging (K=32 step)
    } u;                                  // 20 KiB

    int tid  = threadIdx.x;               // 0..511
    int b    = blockIdx.y;
    int n0   = blockIdx.x * 256;          // out-row base (0 or 256)
    int wave = tid >> 6, lane = tid & 63;
    int q = lane >> 4, l16 = lane & 15;

    sDn[tid] = dnorm[(size_t)b * NN + tid];
    if (tid < 128) sBias[tid] = bias[tid];

    // ---------------- phase 1: h1[b] -> hs ----------------
    {
        int wr1 = wave >> 2;              // 0..1  (64-row group)
        int wc1 = wave & 3;               // 0..3  (32-col group)

        // Wt fragments for this wave's 32-col group, all K=128, in registers.
        bfrag wreg[4][2];
        #pragma unroll
        for (int kt4 = 0; kt4 < 4; kt4++)
            #pragma unroll
            for (int j = 0; j < 2; j++) {
                int g = wc1 * 32 + j * 16 + l16;
                wreg[kt4][j] = *(const bfrag*)(Wt + (size_t)g * FIN + kt4 * 32 + q * 8);
            }

        // 1-deep prefetch across the 8 (chunk,half) stages
        float4 xld[4];
        #pragma unroll
        for (int jj = 0; jj < 4; jj++) {          // stage 0: c=0, kh=0
            int linear = tid + jj * 512;
            int m = linear >> 4, k4 = (linear & 15) << 2;
            xld[jj] = *(const float4*)(x + ((size_t)b * NN + 0 + m) * FIN + 0 + k4);
        }

        for (int c = 0; c < 4; c++) {
            int m0 = c * 128;
            f32x4 acc2[4][2];
            #pragma unroll
            for (int i = 0; i < 4; i++)
                #pragma unroll
                for (int j = 0; j < 2; j++) acc2[i][j] = (f32x4)(0.f);

            for (int kh = 0; kh < 2; kh++) {
                // write current stage from regs
                #pragma unroll
                for (int jj = 0; jj < 4; jj++) {
                    int linear = tid + jj * 512;         // 0..2047
                    int m = linear >> 4, k4 = (linear & 15) << 2;
                    *(ushort4*)&u.As1[m][k4] = f2bf4(xld[jj]);
                }
                __syncthreads();
                // issue next stage's loads (fly under the MFMAs)
                int s = c * 2 + kh + 1;                  // next stage index
                if (s < 8) {
                    int cn = s >> 1, khn = s & 1;
                    #pragma unroll
                    for (int jj = 0; jj < 4; jj++) {
                        int linear = tid + jj * 512;
                        int m = linear >> 4, k4 = (linear & 15) << 2;
                        xld[jj] = *(const float4*)(x + ((size_t)b * NN + cn * 128 + m) * FIN + khn * 64 + k4);
                    }
                }
                #pragma unroll
                for (int kt2 = 0; kt2 < 2; kt2++) {
                    int kt4 = kh * 2 + kt2;              // accumulation order 0,1,2,3
                    bfrag aF[4];
                    #pragma unroll
                    for (int i = 0; i < 4; i++)
                        aF[i] = *(const bfrag*)&u.As1[wr1 * 64 + i * 16 + l16][kt2 * 32 + q * 8];
                    #pragma unroll
                    for (int i = 0; i < 4; i++)
                        #pragma unroll
                        for (int j = 0; j < 2; j++)
                            acc2[i][j] = __builtin_amdgcn_mfma_f32_16x16x32_bf16(aF[i], wreg[kt4][j], acc2[i][j], 0, 0, 0);
                }
                __syncthreads();
            }
            // epilogue: Dm scale + round, store hs[g][m] (4 consecutive m)
            #pragma unroll
            for (int i = 0; i < 4; i++) {
                int mb = m0 + wr1 * 64 + i * 16 + q * 4;
                float d0 = sDn[mb], d1 = sDn[mb + 1], d2 = sDn[mb + 2], d3 = sDn[mb + 3];
                #pragma unroll
                for (int j = 0; j < 2; j++) {
                    int g = wc1 * 32 + j * 16 + l16;
                    f32x4 cc = acc2[i][j];
                    ushort4 v;
                    v.x = f2bf(cc[0] * d0); v.y = f2bf(cc[1] * d1);
                    v.z = f2bf(cc[2] * d2); v.w = f2bf(cc[3] * d3);
                    *(ushort4*)&hs[g][mb] = v;
                }
            }
        }
    }
    __syncthreads();   // hs complete; As1 dead -> As2 may overwrite

    // ---------------- phase 2: out = relu(Dn * (adj @ hs) + b) --------------
    {
        int wr = wave >> 1;               // 0..3  (64-row group of 256)
        int wc = wave & 1;                // 0..1  (64-col group)
        f32x4 acc[4][4];
        #pragma unroll
        for (int i = 0; i < 4; i++)
            #pragma unroll
            for (int j = 0; j < 4; j++) acc[i][j] = (f32x4)(0.f);

        // 2-deep prologue: lda <- kt=0, ldb <- kt=32
        float4 lda[4], ldb[4];
        #pragma unroll
        for (int jj = 0; jj < 4; jj++) {
            int linear = tid + jj * 512;             // 0..2047
            int m = linear >> 3, k4 = (linear & 7) << 2;
            lda[jj] = *(const float4*)(adj + ((size_t)b * NN + n0 + m) * NN + 0 + k4);
        }
        #pragma unroll
        for (int jj = 0; jj < 4; jj++) {
            int linear = tid + jj * 512;
            int m = linear >> 3, k4 = (linear & 7) << 2;
            ldb[jj] = *(const float4*)(adj + ((size_t)b * NN + n0 + m) * NN + 32 + k4);
        }

        for (int kt2 = 0; kt2 < NN; kt2 += 64) {
            // ---- sub-step A: kt = kt2 (data in lda) ----
            #pragma unroll
            for (int jj = 0; jj < 4; jj++) {
                int linear = tid + jj * 512;
                int m = linear >> 3, k4 = (linear & 7) << 2;
                *(ushort4*)&u.As2[m][k4] = f2bf4(lda[jj]);
            }
            __syncthreads();
            if (kt2 + 64 < NN) {                     // refill lda <- kt2+64
                #pragma unroll
                for (int jj = 0; jj < 4; jj++) {
                    int linear = tid + jj * 512;
                    int m = linear >> 3, k4 = (linear & 7) << 2;
                    lda[jj] = *(const float4*)(adj + ((size_t)b * NN + n0 + m) * NN + kt2 + 64 + k4);
                }
            }
            {
                bfrag aF[4], bF[4];
                #pragma unroll
                for (int i = 0; i < 4; i++) aF[i] = *(const bfrag*)&u.As2[wr * 64 + i * 16 + l16][q * 8];
                #pragma unroll
                for (int j = 0; j < 4; j++) bF[j] = *(const bfrag*)&hs[wc * 64 + j * 16 + l16][kt2 + q * 8];
                #pragma unroll
                for (int i = 0; i < 4; i++)
                    #pragma unroll
                    for (int j = 0; j < 4; j++)
                        acc[i][j] = __builtin_amdgcn_mfma_f32_16x16x32_bf16(aF[i], bF[j], acc[i][j], 0, 0, 0);
            }
            __syncthreads();

            // ---- sub-step B: kt = kt2 + 32 (data in ldb) ----
            #pragma unroll
            for (int jj = 0; jj < 4; jj++) {
                int linear = tid + jj * 512;
                int m = linear >> 3, k4 = (linear & 7) << 2;
                *(ushort4*)&u.As2[m][k4] = f2bf4(ldb[jj]);
            }
            __syncthreads();
            if (kt2 + 96 < NN) {                     // refill ldb <- kt2+96
                #pragma unroll
                for (int jj = 0; jj < 4; jj++) {
                    int linear = tid + jj * 512;
                    int m = linear >> 3, k4 = (linear & 7) << 2;
                    ldb[jj] = *(const float4*)(adj + ((size_t)b * NN + n0 + m) * NN + kt2 + 96 + k4);
                }
            }
            {
                bfrag aF[4], bF[4];
                #pragma unroll
                for (int i = 0; i < 4; i++) aF[i] = *(const bfrag*)&u.As2[wr * 64 + i * 16 + l16][q * 8];
                #pragma unroll
                for (int j = 0; j < 4; j++) bF[j] = *(const bfrag*)&hs[wc * 64 + j * 16 + l16][kt2 + 32 + q * 8];
                #pragma unroll
                for (int i = 0; i < 4; i++)
                    #pragma unroll
                    for (int j = 0; j < 4; j++)
                        acc[i][j] = __builtin_amdgcn_mfma_f32_16x16x32_bf16(aF[i], bF[j], acc[i][j], 0, 0, 0);
            }
            __syncthreads();
        }

        // epilogue: Dn scale + bias + relu, fp32 store
        #pragma unroll
        for (int i = 0; i < 4; i++) {
            int rloc = wr * 64 + i * 16 + q * 4;
            float d0 = sDn[n0 + rloc],     d1 = sDn[n0 + rloc + 1];
            float d2 = sDn[n0 + rloc + 2], d3 = sDn[n0 + rloc + 3];
            #pragma unroll
            for (int j = 0; j < 4; j++) {
                int col = wc * 64 + j * 16 + l16;
                float bsv = sBias[col];
                f32x4 c = acc[i][j];
                float* o = out + ((size_t)b * NN + n0 + rloc) * FOUT + col;
                o[0 * FOUT] = fmaxf(fmaf(c[0], d0, bsv), 0.f);
                o[1 * FOUT] = fmaxf(fmaf(c[1], d1, bsv), 0.f);
                o[2 * FOUT] = fmaxf(fmaf(c[2], d2, bsv), 0.f);
                o[3 * FOUT] = fmaxf(fmaf(c[3], d3, bsv), 0.f);
            }
        }
    }
}

extern "C" void kernel_launch(void* const* d_in, const int* in_sizes, int n_in,
                              void* d_out, int out_size, void* d_ws, size_t ws_size,
                              hipStream_t stream) {
    const float* adj  = (const float*)d_in[0];
    const float* x    = (const float*)d_in[1];
    const float* W    = (const float*)d_in[2];
    const float* bias = (const float*)d_in[3];
    float* out = (float*)d_out;

    char* ws = (char*)d_ws;
    float* dnorm = (float*)ws;                                   // 65536 f32 = 256 KB
    u16*   Wt    = (u16*)(ws + 262144);                          // 16384 bf16 = 32 KB

    hipLaunchKernelGGL(k_prep,  dim3(64), dim3(256), 0, stream, W, Wt);
    hipLaunchKernelGGL(k_deg,   dim3(BATCH * NN / 4), dim3(256), 0, stream, adj, dnorm);
    hipLaunchKernelGGL(k_fused, dim3(2, BATCH), dim3(512), 0, stream,
                       x, Wt, adj, dnorm, bias, out);
}